// Round 7
// baseline (206.283 us; speedup 1.0000x reference)
//
#include <hip/hip_runtime.h>
#include <math.h>

// B=8, T=4096, H=8, D=64, fp32.
// R6 structure + airtight load-depth forcing:
//   k_partial : reads inputs ONCE, 16 loads materialized via one asm (64 VGPR
//               live) -> full vmcnt depth; writes partial-out + Z
//   k_scan    : scans chunk aggregates IN-PLACE (P overwrites Z)
//   k_final   : RMW fix-up, 8 out-loads materialized the same way; nt store
#define BB 8
#define TT 4096
#define HH 8
#define NCV 512
#define LCV (TT / NCV)        // 8 steps per chunk
#define GRID (BB * NCV)       // 4096 blocks

typedef float f32x4 __attribute__((ext_vector_type(4)));

__device__ __forceinline__ float sigmoidf_(float x) {
    return 1.0f / (1.0f + expf(-x));
}

// ---------------------------------------------------------------------------
// K1: per-(b,chunk) block of 128 threads (thread = (h,d4), f32x4 over D).
// All 16 dwordx4 loads issued before ONE asm barrier that holds all 16
// results in registers -> single s_waitcnt vmcnt(0), maximal in-flight depth.
// ---------------------------------------------------------------------------
__global__ __launch_bounds__(128)
void k_partial(const f32x4* __restrict__ vals, const f32x4* __restrict__ aux,
               const float* __restrict__ w, f32x4* __restrict__ out,
               f32x4* __restrict__ Z) {
    const int blk = blockIdx.x;
    const int b = blk >> 9;            // blk / NCV
    const int c = blk & (NCV - 1);
    const int tid = threadIdx.x;
    const int h = tid >> 4;

    const float alpha = sigmoidf_(w[h]);
    const float onem  = 1.0f - alpha;
    const float fa    = (onem / fmaxf(onem, 1e-6f)) * alpha;

    // f32x4 index: ((b*T+t)*H + h)*D/4 + d4 = (b*T+t)*128 + tid
    const int base = (b * TT + c * LCV) * 128 + tid;

    f32x4 v0 = vals[base + 0 * 128];
    f32x4 v1 = vals[base + 1 * 128];
    f32x4 v2 = vals[base + 2 * 128];
    f32x4 v3 = vals[base + 3 * 128];
    f32x4 v4 = vals[base + 4 * 128];
    f32x4 v5 = vals[base + 5 * 128];
    f32x4 v6 = vals[base + 6 * 128];
    f32x4 v7 = vals[base + 7 * 128];
    f32x4 a0 = aux[base + 0 * 128];
    f32x4 a1 = aux[base + 1 * 128];
    f32x4 a2 = aux[base + 2 * 128];
    f32x4 a3 = aux[base + 3 * 128];
    f32x4 a4 = aux[base + 4 * 128];
    f32x4 a5 = aux[base + 5 * 128];
    f32x4 a6 = aux[base + 6 * 128];
    f32x4 a7 = aux[base + 7 * 128];
    // One indivisible materialization point: all 16 loads must be issued
    // before this, and all 16 results are simultaneously register-live.
    asm volatile("" : "+v"(v0), "+v"(v1), "+v"(v2), "+v"(v3),
                      "+v"(v4), "+v"(v5), "+v"(v6), "+v"(v7),
                      "+v"(a0), "+v"(a1), "+v"(a2), "+v"(a3),
                      "+v"(a4), "+v"(a5), "+v"(a6), "+v"(a7));

    f32x4 y; y.x = 0.f; y.y = 0.f; y.z = 0.f; y.w = 0.f;
#define STEP(V, A, I)                                                   \
    y.x = alpha * y.x + onem * (V).x + fa * (A).x;                      \
    y.y = alpha * y.y + onem * (V).y + fa * (A).y;                      \
    y.z = alpha * y.z + onem * (V).z + fa * (A).z;                      \
    y.w = alpha * y.w + onem * (V).w + fa * (A).w;                      \
    out[base + (I) * 128] = y;
    STEP(v0, a0, 0) STEP(v1, a1, 1) STEP(v2, a2, 2) STEP(v3, a3, 3)
    STEP(v4, a4, 4) STEP(v5, a5, 5) STEP(v6, a6, 6) STEP(v7, a7, 7)
#undef STEP
    Z[(b * NCV + c) * 128 + tid] = y;  // chunk aggregate
}

// ---------------------------------------------------------------------------
// K2: Kogge-Stone scan over the NCV chunk aggregates, IN-PLACE (P == Z).
// Block = (b, h, d8): 512 blocks, NCV threads (thread = chunk c).
// All global reads complete before the first global write; each block
// writes exactly the slice it read -> in-place safe.
// P[c] = alpha^(L*c) * v0 + S_inc[c-1]; P[0] = v0. Row stride 9 floats.
// ---------------------------------------------------------------------------
__global__ __launch_bounds__(NCV)
void k_scan(float4* __restrict__ ZP, const float* __restrict__ v0,
            const float* __restrict__ w) {
    __shared__ float lds[NCV][9];

    const int blk = blockIdx.x;        // b*64 + h*8 + d8
    const int b  = blk >> 6;
    const int h  = (blk >> 3) & 7;
    const int d8 = blk & 7;
    const int r4 = h * 16 + d8 * 2;
    const int tid = threadIdx.x;

    const float alpha = sigmoidf_(w[h]);
    const float aL = powf(alpha, (float)LCV);

    {
        float4 z0 = ZP[(b * NCV + tid) * 128 + r4];
        float4 z1 = ZP[(b * NCV + tid) * 128 + r4 + 1];
        lds[tid][0] = z0.x; lds[tid][1] = z0.y; lds[tid][2] = z0.z; lds[tid][3] = z0.w;
        lds[tid][4] = z1.x; lds[tid][5] = z1.y; lds[tid][6] = z1.z; lds[tid][7] = z1.w;
    }
    __syncthreads();

    const int c = tid;
    float s[8];
#pragma unroll
    for (int k = 0; k < 8; ++k) s[k] = lds[c][k];

    float m = aL;
    for (int off = 1; off < NCV; off <<= 1) {
        float tmp[8];
        const bool act = (c >= off);
        if (act) {
#pragma unroll
            for (int k = 0; k < 8; ++k) tmp[k] = lds[c - off][k];
        }
        __syncthreads();
        if (act) {
#pragma unroll
            for (int k = 0; k < 8; ++k) { s[k] += m * tmp[k]; lds[c][k] = s[k]; }
        }
        m *= m;
        __syncthreads();
    }

    const float pc = powf(alpha, (float)(LCV * c));
    const float4* v04 = (const float4*)v0;
#pragma unroll
    for (int k = 0; k < 2; ++k) {
        float4 vv = v04[r4 + k];
        float4 pr;
        if (c == 0) {
            pr = vv;
        } else {
            pr.x = pc * vv.x + lds[c - 1][k * 4 + 0];
            pr.y = pc * vv.y + lds[c - 1][k * 4 + 1];
            pr.z = pc * vv.z + lds[c - 1][k * 4 + 2];
            pr.w = pc * vv.w + lds[c - 1][k * 4 + 3];
        }
        ZP[(b * NCV + c) * 128 + r4 + k] = pr;   // in-place: P over Z
    }
}

// ---------------------------------------------------------------------------
// K3: elementwise fix-up: out[t] += alpha^(i+1) * P[c]   (t = c*L + i).
// Reads out (L3-hot from K1) + P (L3-hot from K2). Same materialization
// trick for the 8 out-loads + p. Final store is non-temporal.
// ---------------------------------------------------------------------------
__global__ __launch_bounds__(128)
void k_final(const float* __restrict__ w, const f32x4* __restrict__ P,
             f32x4* __restrict__ out) {
    const int blk = blockIdx.x;
    const int b = blk >> 9;
    const int c = blk & (NCV - 1);
    const int tid = threadIdx.x;
    const int h = tid >> 4;

    const float alpha = sigmoidf_(w[h]);
    const int base = (b * TT + c * LCV) * 128 + tid;

    f32x4 p  = P[(b * NCV + c) * 128 + tid];
    f32x4 o0 = out[base + 0 * 128];
    f32x4 o1 = out[base + 1 * 128];
    f32x4 o2 = out[base + 2 * 128];
    f32x4 o3 = out[base + 3 * 128];
    f32x4 o4 = out[base + 4 * 128];
    f32x4 o5 = out[base + 5 * 128];
    f32x4 o6 = out[base + 6 * 128];
    f32x4 o7 = out[base + 7 * 128];
    asm volatile("" : "+v"(p),
                      "+v"(o0), "+v"(o1), "+v"(o2), "+v"(o3),
                      "+v"(o4), "+v"(o5), "+v"(o6), "+v"(o7));

    float coef = alpha;
#define FIX(O, I)                                                       \
    (O).x += coef * p.x; (O).y += coef * p.y;                           \
    (O).z += coef * p.z; (O).w += coef * p.w;                           \
    __builtin_nontemporal_store((O), &out[base + (I) * 128]);           \
    coef *= alpha;
    FIX(o0, 0) FIX(o1, 1) FIX(o2, 2) FIX(o3, 3)
    FIX(o4, 4) FIX(o5, 5) FIX(o6, 6) FIX(o7, 7)
#undef FIX
}

// ---------------------------------------------------------------------------
extern "C" void kernel_launch(void* const* d_in, const int* in_sizes, int n_in,
                              void* d_out, int out_size, void* d_ws, size_t ws_size,
                              hipStream_t stream) {
    const f32x4* vals = (const f32x4*)d_in[0];   // values  [B,T,H,D]
    const f32x4* aux  = (const f32x4*)d_in[1];   // aux     [B,T,H,D]
    const float* v0   = (const float*)d_in[2];   // v0      [H,D] = 512
    const float* w    = (const float*)d_in[3];   // weight  [H] = 8
    f32x4* out = (f32x4*)d_out;

    // Workspace: single Z/P buffer, B*NCV*128 f32x4 = 8.39 MB (in-place scan).
    f32x4* ZP = (f32x4*)d_ws;

    k_partial<<<GRID, 128, 0, stream>>>(vals, aux, w, out, ZP);
    k_scan<<<BB * HH * 8, NCV, 0, stream>>>((float4*)ZP, v0, w);
    k_final<<<GRID, 128, 0, stream>>>(w, ZP, out);
}

// Round 8
// 195.964 us; speedup vs baseline: 1.0527x; 1.0527x over previous
//
#include <hip/hip_runtime.h>
#include <math.h>

// B=8, T=4096, H=8, D=64, fp32.
// Session-best configuration (R0, measured 196.45 us) — pure revert.
// 8 rounds of A/B established: combined-traffic ceiling ~3.3 TB/s for this
// shape (source-independent: L3-resident replays run at identical speed),
// occupancy/issue-depth/byte-shuffle levers all null, grid-barrier fusion
// catastrophic. This 3-kernel structure at 208R+136W MB is the floor.
#define BB 8
#define TT 4096
#define HH 8
#define DD 64
#define NC 256            // chunks along T
#define LL (TT / NC)      // 16 steps per chunk

__device__ __forceinline__ float sigmoidf_(float x) {
    return 1.0f / (1.0f + expf(-x));
}

// K1: per-(b,chunk) block of 128 threads (thread = (h,d4), float4 over D).
// Computes zero-init partial scan y0[t], streams it to out, writes chunk
// aggregate Z = y0[L-1].
__global__ __launch_bounds__(128)
void k_partial(const float4* __restrict__ vals, const float4* __restrict__ aux,
               const float* __restrict__ w, float4* __restrict__ out,
               float4* __restrict__ Z) {
    const int blk = blockIdx.x;
    const int b = blk / NC, c = blk % NC;
    const int tid = threadIdx.x;
    const int h = tid >> 4;

    const float alpha = sigmoidf_(w[h]);
    const float onem  = 1.0f - alpha;
    const float fa    = (onem / fmaxf(onem, 1e-6f)) * alpha;

    // float4 index: ((b*T+t)*H + h)*D/4 + d4 = (b*T+t)*128 + tid
    int base = (b * TT + c * LL) * 128 + tid;

    float4 y = make_float4(0.f, 0.f, 0.f, 0.f);
#pragma unroll
    for (int i = 0; i < LL; ++i) {
        float4 v = vals[base + i * 128];
        float4 a = aux[base + i * 128];
        y.x = alpha * y.x + (onem * v.x + fa * a.x);
        y.y = alpha * y.y + (onem * v.y + fa * a.y);
        y.z = alpha * y.z + (onem * v.z + fa * a.z);
        y.w = alpha * y.w + (onem * v.w + fa * a.w);
        out[base + i * 128] = y;
    }
    Z[(b * NC + c) * 128 + tid] = y;
}

// K2: Kogge-Stone scan over the NC chunk aggregates.
// Block = (b, h, d-half): 8*8*2 = 128 blocks, 256 threads (thread = chunk c).
// Each thread owns one chunk row of 32 floats (8 float4 of its d-half).
// Combine: S[c] += aL^off * S[c-off].  P[c] = aL^c * v0 + S_inc[c-1].
__global__ __launch_bounds__(256)
void k_scan(const float4* __restrict__ Z, const float* __restrict__ v0,
            const float* __restrict__ w, float4* __restrict__ P) {
    __shared__ float lds[NC][33];   // +1 pad: stride 33 banks -> conflict-free

    const int blk = blockIdx.x;       // b*16 + h*2 + dh
    const int b  = blk >> 4;
    const int h  = (blk >> 1) & 7;
    const int dh = blk & 1;
    const int r4base = h * 16 + dh * 8;
    const int tid = threadIdx.x;

    const float alpha = sigmoidf_(w[h]);
    const float aL = powf(alpha, (float)LL);

    // Cooperative load: NC*8 = 2048 float4s, 8 per c-row.
#pragma unroll
    for (int it = 0; it < 8; ++it) {
        int idx = it * 256 + tid;
        int c = idx >> 3, k = idx & 7;
        float4 z = Z[(b * NC + c) * 128 + r4base + k];
        lds[c][k * 4 + 0] = z.x;
        lds[c][k * 4 + 1] = z.y;
        lds[c][k * 4 + 2] = z.z;
        lds[c][k * 4 + 3] = z.w;
    }
    __syncthreads();

    const int c = tid;    // thread c owns chunk c's 32-float row
    float s[32];
#pragma unroll
    for (int k = 0; k < 32; ++k) s[k] = lds[c][k];

    float m = aL;
    for (int off = 1; off < NC; off <<= 1) {
        float tmp[32];
        const bool act = (c >= off);
        if (act) {
#pragma unroll
            for (int k = 0; k < 32; ++k) tmp[k] = lds[c - off][k];
        }
        __syncthreads();
        if (act) {
#pragma unroll
            for (int k = 0; k < 32; ++k) { s[k] += m * tmp[k]; lds[c][k] = s[k]; }
        }
        m *= m;
        __syncthreads();
    }

    // Carry into chunk c: P[c] = aL^c * v0 + S_inc[c-1]; P[0] = v0.
    const float pc = powf(alpha, (float)(LL * c));
    const float4* v04 = (const float4*)v0;
#pragma unroll
    for (int k = 0; k < 8; ++k) {
        float4 vv = v04[r4base + k];
        float4 pr;
        if (c == 0) {
            pr = vv;
        } else {
            pr.x = pc * vv.x + lds[c - 1][k * 4 + 0];
            pr.y = pc * vv.y + lds[c - 1][k * 4 + 1];
            pr.z = pc * vv.z + lds[c - 1][k * 4 + 2];
            pr.w = pc * vv.w + lds[c - 1][k * 4 + 3];
        }
        P[(b * NC + c) * 128 + r4base + k] = pr;
    }
}

// K3: elementwise fix-up: out[t] += alpha^(i+1) * P[c]   (t = c*L + i).
// Reads out (L3-hot) + P; no re-read of the 128 MB inputs.
__global__ __launch_bounds__(128)
void k_final(const float* __restrict__ w, const float4* __restrict__ P,
             float4* __restrict__ out) {
    const int blk = blockIdx.x;
    const int b = blk / NC, c = blk % NC;
    const int tid = threadIdx.x;
    const int h = tid >> 4;

    const float alpha = sigmoidf_(w[h]);
    const float4 p = P[(b * NC + c) * 128 + tid];
    int base = (b * TT + c * LL) * 128 + tid;

    float coef = alpha;
#pragma unroll
    for (int i = 0; i < LL; ++i) {
        float4 o = out[base + i * 128];
        o.x += coef * p.x;
        o.y += coef * p.y;
        o.z += coef * p.z;
        o.w += coef * p.w;
        out[base + i * 128] = o;
        coef *= alpha;
    }
}

extern "C" void kernel_launch(void* const* d_in, const int* in_sizes, int n_in,
                              void* d_out, int out_size, void* d_ws, size_t ws_size,
                              hipStream_t stream) {
    const float4* vals = (const float4*)d_in[0];   // values  [B,T,H,D]
    const float4* aux  = (const float4*)d_in[1];   // aux     [B,T,H,D]
    const float*  v0   = (const float*)d_in[2];    // v0      [H,D] = 512
    const float*  w    = (const float*)d_in[3];    // weight  [H] = 8
    float4* out = (float4*)d_out;

    // Workspace: Z then P, each B*NC*128 float4 = 4 MB.
    float4* Z = (float4*)d_ws;
    float4* P = Z + (size_t)BB * NC * 128;

    k_partial<<<BB * NC, 128, 0, stream>>>(vals, aux, w, out, Z);
    k_scan<<<BB * HH * 2, 256, 0, stream>>>(Z, v0, w, P);
    k_final<<<BB * NC, 128, 0, stream>>>(w, P, out);
}